// Round 4
// baseline (366.856 us; speedup 1.0000x reference)
//
#include <hip/hip_runtime.h>
#include <hip/hip_bf16.h>

#define NSEQ 2048
#define DM 512
#define BATCH 8
#define GTOT (BATCH * NSEQ)          // 16384
#define INV_T 0.044194173824159216f  // 1/sqrt(512)
#define EPSN 1e-5f

typedef __bf16 bf16_t;
typedef bf16_t bf16x8 __attribute__((ext_vector_type(8)));
typedef float f32x16 __attribute__((ext_vector_type(16)));
typedef unsigned short u16;
typedef unsigned int u32;
typedef unsigned long long u64;

__device__ __forceinline__ u16 f2bf(float f) {
    u32 u = __builtin_bit_cast(u32, f);
    u32 r = (u + 0x7FFFu + ((u >> 16) & 1u)) >> 16;
    return (u16)r;
}

// async global->LDS DMA, 16 B per lane. LDS dest = wave-uniform base + lane*16 B.
__device__ __forceinline__ void async16(const u16* g, u16* l) {
    __builtin_amdgcn_global_load_lds(
        (const __attribute__((address_space(1))) u32*)g,
        (__attribute__((address_space(3))) u32*)l, 16, 0, 0);
}

// BK=64 LDS tile: rows x 64 k-elems (128 B rows), 8 16-B chunks XOR-swizzled by ((row>>1)&7).
__device__ __forceinline__ bf16x8 fragld64(const u16* t, int row, int kc) {
    return *(const bf16x8*)(t + row * 64 + ((kc ^ ((row >> 1) & 7)) << 3));
}

#define MFMA32(a, b, c) __builtin_amdgcn_mfma_f32_32x32x16_bf16(a, b, c, 0, 0, 0)
#define ROWOFF(reg, lh) (((reg) & 3) + 8 * ((reg) >> 2) + 4 * (lh))

// BK=64 staging: 8 issues/thread (4 A + 4 B). Issue u = wave*4+j covers LDS rows
// u*8..u*8+7; lane supplies row u*8+(lane>>3), chunk (lane&7), fetching the
// global chunk that fragld64's XOR expects at that slot.
#define STAGE64(Ag, ldA, Bg, ldB, k0)                                            \
    do {                                                                         \
        _Pragma("unroll") for (int j = 0; j < 4; ++j) {                          \
            const int cg = (lane & 7) ^ ((j * 4 + (lane >> 4)) & 7);             \
            const int dst = (wave * 4 + j) * 512 + lane * 8;                     \
            async16((Ag) + (long)(rS + j * 8) * (ldA) + (k0) + cg * 8, Ab + dst);\
            async16((Bg) + (long)(rS + j * 8) * (ldB) + (k0) + cg * 8, Bb + dst);\
        }                                                                        \
    } while (0)

// ---------------- kernel 1: f32 -> bf16 of X and W; zero ssbuf ----------------
__global__ __launch_bounds__(256) void k_convert(
    const float* __restrict__ X, const float* __restrict__ W,
    u16* __restrict__ Kbf, u16* __restrict__ Wbf, float* __restrict__ ssbuf) {
    const long NK = (long)GTOT * DM / 4;  // 2097152
    const long NW = (long)DM * DM / 4;    // 65536
    const long NS = GTOT / 4;             // 4096
    long i = (long)blockIdx.x * 256 + threadIdx.x;
    if (i < NK) {
        float4 f = ((const float4*)X)[i];
        ushort4 o;
        o.x = f2bf(f.x); o.y = f2bf(f.y); o.z = f2bf(f.z); o.w = f2bf(f.w);
        ((ushort4*)Kbf)[i] = o;
    } else if (i < NK + NW) {
        long j = i - NK;
        float4 f = ((const float4*)W)[j];
        ushort4 o;
        o.x = f2bf(f.x); o.y = f2bf(f.y); o.z = f2bf(f.z); o.w = f2bf(f.w);
        ((ushort4*)Wbf)[j] = o;
    } else if (i < NK + NW + NS) {
        ((float4*)ssbuf)[i - NK - NW] = (float4){0.f, 0.f, 0.f, 0.f};
    }
}

// --- kernel 2: S = mask .* (X X^T) * INV_T (bf16) + row sum-of-squares ---
// 128x128 tile, BK=64, 256 thr, 4 waves (2x2), wave tile 64x64.
// 1-D grid, b = bid&7 -> XCD affinity. f32 mask read fused AND spread across the
// K-loop: 8 dword loads per kt iteration, folded to 2 u32 bitmasks in-register
// (mask values are exactly 0/1), so the 134 MB stream overlaps the MFMA phases
// instead of serializing in the epilogue (round-3 lesson).
__global__ __launch_bounds__(256, 4) void k_sgemm(
    const u16* __restrict__ Kbf, const float* __restrict__ mask,
    u16* __restrict__ Sbuf, float* __restrict__ ssbuf) {
    __shared__ __attribute__((aligned(16))) u16 Ab[8192], Bb[8192];
    const int tid = threadIdx.x, wave = tid >> 6, lane = tid & 63;
    const int l31 = lane & 31, lh = lane >> 5;
    const int wy = wave >> 1, wx = wave & 1;
    const int bid = blockIdx.x;
    const int b = bid & 7;                       // batch -> XCD
    const int ty = (bid >> 3) & 15, tx = bid >> 7;
    const int M0 = ty * 128, N0 = tx * 128;
    const u16* Ag = Kbf + (long)(b * NSEQ + M0) * DM;
    const u16* Bg = Kbf + (long)(b * NSEQ + N0) * DM;
    // per-thread mask base: row (M0 + wy*64 + lh*4), col (N0 + wx*64 + l31)
    const float* mbase =
        mask + ((long)b * NSEQ + M0 + wy * 64) * NSEQ + N0 + wx * 64 + l31;

    const int rS = wave * 32 + (lane >> 3);

    f32x16 acc[2][2];
#pragma unroll
    for (int i = 0; i < 2; ++i)
#pragma unroll
        for (int j = 0; j < 2; ++j)
#pragma unroll
            for (int e = 0; e < 16; ++e) acc[i][j][e] = 0.f;

    u32 mb0 = 0, mb1 = 0;  // bit (reg*2+ni) of mb{mi} = mask != 0

#pragma unroll
    for (int kt = 0; kt < 8; ++kt) {
        const int k0 = kt * 64;
        __syncthreads();
        STAGE64(Ag, DM, Bg, DM, k0);
        __syncthreads();
        // issue this iteration's 8 mask dword loads (latency hidden by MFMAs + TLP)
        float mt[8];
#pragma unroll
        for (int j = 0; j < 8; ++j) {
            const int q = kt * 8 + j;                 // 0..63, static
            const int mi = q >> 5, rem = q & 31;
            const int reg = rem >> 1, ni = rem & 1;
            const int rl = mi * 32 + ROWOFF(reg, lh); // row offset within wave tile
            mt[j] = mbase[(long)rl * NSEQ + ni * 32];
        }
#pragma unroll
        for (int ks = 0; ks < 4; ++ks) {
            const int kc = ks * 2 + lh;
            bf16x8 a0 = fragld64(Ab, wy * 64 + l31, kc);
            bf16x8 a1 = fragld64(Ab, wy * 64 + 32 + l31, kc);
            bf16x8 b0 = fragld64(Bb, wx * 64 + l31, kc);
            bf16x8 b1 = fragld64(Bb, wx * 64 + 32 + l31, kc);
            acc[0][0] = MFMA32(a0, b0, acc[0][0]);
            acc[0][1] = MFMA32(a0, b1, acc[0][1]);
            acc[1][0] = MFMA32(a1, b0, acc[1][0]);
            acc[1][1] = MFMA32(a1, b1, acc[1][1]);
        }
        // fold loaded mask values into the bit registers
#pragma unroll
        for (int j = 0; j < 8; ++j) {
            const int q = kt * 8 + j;
            const u32 bit = (mt[j] != 0.f) ? 1u : 0u;
            if ((q >> 5) == 0) mb0 |= bit << (q & 31);
            else               mb1 |= bit << (q & 31);
        }
    }
    // epilogue: bitmask multiply, bf16 store (L3-cached for k_pv), row sum-of-squares
#pragma unroll
    for (int mi = 0; mi < 2; ++mi) {
        const u32 mbv = mi ? mb1 : mb0;
#pragma unroll
        for (int reg = 0; reg < 16; ++reg) {
            int rl = M0 + wy * 64 + mi * 32 + ROWOFF(reg, lh);
            long rg = (long)b * NSEQ + rl;
            float v = 0.f;
#pragma unroll
            for (int ni = 0; ni < 2; ++ni) {
                int cg = N0 + wx * 64 + ni * 32 + l31;
                float s = ((mbv >> (reg * 2 + ni)) & 1u) ? acc[mi][ni][reg] * INV_T : 0.f;
                v += s * s;
                Sbuf[rg * NSEQ + cg] = f2bf(s);
            }
            v += __shfl_xor(v, 1, 32);
            v += __shfl_xor(v, 2, 32);
            v += __shfl_xor(v, 4, 32);
            v += __shfl_xor(v, 8, 32);
            v += __shfl_xor(v, 16, 32);
            if (l31 == 0) atomicAdd(&ssbuf[rg], v);
        }
    }
}

// ------------- kernel 3: vT[e][g] = elu(W X^T + b), 128x128 BK=64 -------------
__global__ __launch_bounds__(256, 4) void k_vgemm(
    const u16* __restrict__ Wbf, const u16* __restrict__ Kbf,
    const float* __restrict__ bias, u16* __restrict__ vT) {
    __shared__ __attribute__((aligned(16))) u16 Ab[8192], Bb[8192];
    const int tid = threadIdx.x, wave = tid >> 6, lane = tid & 63;
    const int l31 = lane & 31, lh = lane >> 5;
    const int wy = wave >> 1, wx = wave & 1;
    const int M0 = blockIdx.y * 128, N0 = blockIdx.x * 128;
    const u16* Ag = Wbf + (long)M0 * DM;
    const u16* Bg = Kbf + (long)N0 * DM;

    const int rS = wave * 32 + (lane >> 3);

    f32x16 acc[2][2];
#pragma unroll
    for (int i = 0; i < 2; ++i)
#pragma unroll
        for (int j = 0; j < 2; ++j)
#pragma unroll
            for (int e = 0; e < 16; ++e) acc[i][j][e] = 0.f;

    for (int kt = 0; kt < 8; ++kt) {
        const int k0 = kt * 64;
        __syncthreads();
        STAGE64(Ag, DM, Bg, DM, k0);
        __syncthreads();
#pragma unroll
        for (int ks = 0; ks < 4; ++ks) {
            const int kc = ks * 2 + lh;
            bf16x8 a0 = fragld64(Ab, wy * 64 + l31, kc);
            bf16x8 a1 = fragld64(Ab, wy * 64 + 32 + l31, kc);
            bf16x8 b0 = fragld64(Bb, wx * 64 + l31, kc);
            bf16x8 b1 = fragld64(Bb, wx * 64 + 32 + l31, kc);
            acc[0][0] = MFMA32(a0, b0, acc[0][0]);
            acc[0][1] = MFMA32(a0, b1, acc[0][1]);
            acc[1][0] = MFMA32(a1, b0, acc[1][0]);
            acc[1][1] = MFMA32(a1, b1, acc[1][1]);
        }
    }
#pragma unroll
    for (int mi = 0; mi < 2; ++mi) {
#pragma unroll
        for (int reg = 0; reg < 16; ++reg) {
            int e = M0 + wy * 64 + mi * 32 + ROWOFF(reg, lh);
            float bv = bias[e];
#pragma unroll
            for (int ni = 0; ni < 2; ++ni) {
                int g = N0 + wx * 64 + ni * 32 + l31;
                float x = acc[mi][ni][reg] + bv;
                float v = x > 0.f ? x : (__expf(x) - 1.f);
                vT[(long)e * GTOT + g] = f2bf(v);
            }
        }
    }
}

// -------- kernel 4: O = diag(1/max(||S_row||,eps)) * (S V), 128x128 BK=64 ------
// 1-D grid, b = bid&7 -> XCD affinity (vT batch slice 2 MiB + S panels stay in L2).
__global__ __launch_bounds__(256, 4) void k_pv(
    const u16* __restrict__ Sbuf, const u16* __restrict__ vT,
    const float* __restrict__ ssbuf, float* __restrict__ Out) {
    __shared__ __attribute__((aligned(16))) u16 Ab[8192], Bb[8192];
    __shared__ float sc[128];
    const int tid = threadIdx.x, wave = tid >> 6, lane = tid & 63;
    const int l31 = lane & 31, lh = lane >> 5;
    const int wy = wave >> 1, wx = wave & 1;
    const int bid = blockIdx.x;
    const int b = bid & 7;                       // batch -> XCD
    const int r = bid >> 3;
    const int tx = r & 3, ty = r >> 2;
    const int M0 = ty * 128, N0 = tx * 128;
    const u16* Ag = Sbuf + (long)(b * NSEQ + M0) * NSEQ;
    const u16* Bg = vT + (long)N0 * GTOT + b * NSEQ;

    if (tid < 128) {
        float v = ssbuf[b * NSEQ + M0 + tid];
        sc[tid] = 1.f / fmaxf(sqrtf(v), EPSN);
    }

    const int rS = wave * 32 + (lane >> 3);

    f32x16 acc[2][2];
#pragma unroll
    for (int i = 0; i < 2; ++i)
#pragma unroll
        for (int j = 0; j < 2; ++j)
#pragma unroll
            for (int e = 0; e < 16; ++e) acc[i][j][e] = 0.f;

    for (int kt = 0; kt < 32; ++kt) {
        const int k0 = kt * 64;
        __syncthreads();
        STAGE64(Ag, NSEQ, Bg, GTOT, k0);
        __syncthreads();
#pragma unroll
        for (int ks = 0; ks < 4; ++ks) {
            const int kc = ks * 2 + lh;
            bf16x8 a0 = fragld64(Ab, wy * 64 + l31, kc);
            bf16x8 a1 = fragld64(Ab, wy * 64 + 32 + l31, kc);
            bf16x8 b0 = fragld64(Bb, wx * 64 + l31, kc);
            bf16x8 b1 = fragld64(Bb, wx * 64 + 32 + l31, kc);
            acc[0][0] = MFMA32(a0, b0, acc[0][0]);
            acc[0][1] = MFMA32(a0, b1, acc[0][1]);
            acc[1][0] = MFMA32(a1, b0, acc[1][0]);
            acc[1][1] = MFMA32(a1, b1, acc[1][1]);
        }
    }
#pragma unroll
    for (int mi = 0; mi < 2; ++mi) {
#pragma unroll
        for (int reg = 0; reg < 16; ++reg) {
            int rl = wy * 64 + mi * 32 + ROWOFF(reg, lh);
            float s = sc[rl];
            float* op = Out + ((long)b * NSEQ + M0 + rl) * DM;
#pragma unroll
            for (int ni = 0; ni < 2; ++ni) {
                int d = N0 + wx * 64 + ni * 32 + l31;
                op[d] = acc[mi][ni][reg] * s;
            }
        }
    }
}

extern "C" void kernel_launch(void* const* d_in, const int* in_sizes, int n_in,
                              void* d_out, int out_size, void* d_ws, size_t ws_size,
                              hipStream_t stream) {
    const float* X = (const float*)d_in[0];
    const float* mask = (const float*)d_in[1];
    const float* W = (const float*)d_in[2];
    const float* bias = (const float*)d_in[3];
    float* out = (float*)d_out;

    char* ws = (char*)d_ws;
    u16* Kbf = (u16*)ws;                           // 16 MiB
    u16* Wbf = (u16*)(ws + 16777216);              // 512 KiB
    u16* vT = (u16*)(ws + 17301504);               // 16 MiB
    u16* Sbuf = (u16*)(ws + 34078720);             // 64 MiB
    float* ssbuf = (float*)(ws + 101187584);       // 64 KiB

    k_convert<<<8464, 256, 0, stream>>>(X, W, Kbf, Wbf, ssbuf);
    k_vgemm<<<dim3(128, 4), 256, 0, stream>>>(Wbf, Kbf, bias, vT);
    k_sgemm<<<2048, 256, 0, stream>>>(Kbf, mask, Sbuf, ssbuf);
    k_pv<<<512, 256, 0, stream>>>(Sbuf, vT, ssbuf, out);
}

// Round 5
// 350.596 us; speedup vs baseline: 1.0464x; 1.0464x over previous
//
#include <hip/hip_runtime.h>
#include <hip/hip_bf16.h>

#define NSEQ 2048
#define DM 512
#define BATCH 8
#define GTOT (BATCH * NSEQ)          // 16384
#define INV_T 0.044194173824159216f  // 1/sqrt(512)
#define EPSN 1e-5f

typedef __bf16 bf16_t;
typedef bf16_t bf16x8 __attribute__((ext_vector_type(8)));
typedef float f32x16 __attribute__((ext_vector_type(16)));
typedef unsigned short u16;
typedef unsigned int u32;
typedef unsigned long long u64;

__device__ __forceinline__ u16 f2bf(float f) {
    u32 u = __builtin_bit_cast(u32, f);
    u32 r = (u + 0x7FFFu + ((u >> 16) & 1u)) >> 16;
    return (u16)r;
}

// async global->LDS DMA, 16 B per lane. LDS dest = wave-uniform base + lane*16 B.
__device__ __forceinline__ void async16(const u16* g, u16* l) {
    __builtin_amdgcn_global_load_lds(
        (const __attribute__((address_space(1))) u32*)g,
        (__attribute__((address_space(3))) u32*)l, 16, 0, 0);
}

// BK=64 LDS tile: rows x 64 k-elems (128 B rows), 8 16-B chunks XOR-swizzled by ((row>>1)&7).
__device__ __forceinline__ bf16x8 fragld64(const u16* t, int row, int kc) {
    return *(const bf16x8*)(t + row * 64 + ((kc ^ ((row >> 1) & 7)) << 3));
}

#define MFMA32(a, b, c) __builtin_amdgcn_mfma_f32_32x32x16_bf16(a, b, c, 0, 0, 0)
#define ROWOFF(reg, lh) (((reg) & 3) + 8 * ((reg) >> 2) + 4 * (lh))

// BK=64 staging for 4-wave/256-thr kernels: 8 issues/thread (4 A + 4 B).
// Issue u = wave*4+j covers LDS rows u*8..u*8+7; lane supplies row u*8+(lane>>3),
// slot (lane&7), fetching the global chunk fragld64's XOR expects there.
#define STAGE64(Ag, ldA, Bg, ldB, k0)                                            \
    do {                                                                         \
        _Pragma("unroll") for (int j = 0; j < 4; ++j) {                          \
            const int cg = (lane & 7) ^ ((j * 4 + (lane >> 4)) & 7);             \
            const int dst = (wave * 4 + j) * 512 + lane * 8;                     \
            async16((Ag) + (long)(rS + j * 8) * (ldA) + (k0) + cg * 8, Ab + dst);\
            async16((Bg) + (long)(rS + j * 8) * (ldB) + (k0) + cg * 8, Bb + dst);\
        }                                                                        \
    } while (0)

// BK=64 staging for 8-wave/512-thr kernels: 4 issues/thread (2 A + 2 B).
// Issue u = wave*2+j; XOR term (u*4 + lane>>4)&7 = (j*4 + lane>>4)&7 (wave*8 == 0 mod 8).
#define STAGE64W8(Ag, ldA, Bg, ldB, k0)                                          \
    do {                                                                         \
        _Pragma("unroll") for (int j = 0; j < 2; ++j) {                          \
            const int cg = (lane & 7) ^ ((j * 4 + (lane >> 4)) & 7);             \
            const int rr = wave * 16 + j * 8 + (lane >> 3);                      \
            const int dst = (wave * 2 + j) * 512 + lane * 8;                     \
            async16((Ag) + (long)rr * (ldA) + (k0) + cg * 8, Ab + dst);          \
            async16((Bg) + (long)rr * (ldB) + (k0) + cg * 8, Bb + dst);          \
        }                                                                        \
    } while (0)

// --- kernel 1: mask -> bits (ballot), f32 -> bf16 of X and W, zero ssbuf ---
// Blocks [0, 32768): 1024 mask floats each; lane i holds col base+i, one
// __ballot per 64 cols emits the u64 in exactly the consumer's bit layout.
__global__ __launch_bounds__(256) void k_convert(
    const float* __restrict__ X, const float* __restrict__ W,
    const float* __restrict__ mask, u16* __restrict__ Kbf, u16* __restrict__ Wbf,
    u64* __restrict__ Mbits, float* __restrict__ ssbuf) {
    const int bid = blockIdx.x;
    if (bid < 32768) {
        const int w = threadIdx.x >> 6, lane = threadIdx.x & 63;
        const long base = (long)bid * 1024 + w * 256;
#pragma unroll
        for (int j = 0; j < 4; ++j) {
            float m = mask[base + j * 64 + lane];
            u64 bits = __ballot(m != 0.f);
            if (lane == 0) Mbits[(base + j * 64) >> 6] = bits;
        }
        return;
    }
    const long NK = (long)GTOT * DM / 4;  // 2097152
    const long NW = (long)DM * DM / 4;    // 65536
    const long NS = GTOT / 4;             // 4096
    long i = (long)(bid - 32768) * 256 + threadIdx.x;
    if (i < NK) {
        float4 f = ((const float4*)X)[i];
        ushort4 o;
        o.x = f2bf(f.x); o.y = f2bf(f.y); o.z = f2bf(f.z); o.w = f2bf(f.w);
        ((ushort4*)Kbf)[i] = o;
    } else if (i < NK + NW) {
        long j = i - NK;
        float4 f = ((const float4*)W)[j];
        ushort4 o;
        o.x = f2bf(f.x); o.y = f2bf(f.y); o.z = f2bf(f.z); o.w = f2bf(f.w);
        ((ushort4*)Wbf)[j] = o;
    } else if (i < NK + NW + NS) {
        ((float4*)ssbuf)[i - NK - NW] = (float4){0.f, 0.f, 0.f, 0.f};
    }
}

// --- kernel 2: S = bitmask .* (X X^T) * INV_T (bf16) + row sum-of-squares ---
// 128x128 tile, BK=64, 256 thr, 4 waves (2x2), wave tile 64x64.
// 1-D grid, b = bid&7 -> XCD affinity. Mask consumed as L3-hot bits (round-0
// proven structure: 78.5 us, MfmaUtil 17.6% = this structure's ceiling).
__global__ __launch_bounds__(256, 4) void k_sgemm(
    const u16* __restrict__ Kbf, const u32* __restrict__ Mw,
    u16* __restrict__ Sbuf, float* __restrict__ ssbuf) {
    __shared__ __attribute__((aligned(16))) u16 Ab[8192], Bb[8192];
    const int tid = threadIdx.x, wave = tid >> 6, lane = tid & 63;
    const int l31 = lane & 31, lh = lane >> 5;
    const int wy = wave >> 1, wx = wave & 1;
    const int bid = blockIdx.x;
    const int b = bid & 7;                       // batch -> XCD
    const int ty = (bid >> 3) & 15, tx = bid >> 7;
    const int M0 = ty * 128, N0 = tx * 128;
    const u16* Ag = Kbf + (long)(b * NSEQ + M0) * DM;
    const u16* Bg = Kbf + (long)(b * NSEQ + N0) * DM;
    const u32* Mb = Mw + (long)b * NSEQ * 64;    // 64 u32 words per row

    const int rS = wave * 32 + (lane >> 3);

    f32x16 acc[2][2];
#pragma unroll
    for (int i = 0; i < 2; ++i)
#pragma unroll
        for (int j = 0; j < 2; ++j)
#pragma unroll
            for (int e = 0; e < 16; ++e) acc[i][j][e] = 0.f;

    for (int kt = 0; kt < 8; ++kt) {
        const int k0 = kt * 64;
        __syncthreads();
        STAGE64(Ag, DM, Bg, DM, k0);
        __syncthreads();
#pragma unroll
        for (int ks = 0; ks < 4; ++ks) {
            const int kc = ks * 2 + lh;
            bf16x8 a0 = fragld64(Ab, wy * 64 + l31, kc);
            bf16x8 a1 = fragld64(Ab, wy * 64 + 32 + l31, kc);
            bf16x8 b0 = fragld64(Bb, wx * 64 + l31, kc);
            bf16x8 b1 = fragld64(Bb, wx * 64 + 32 + l31, kc);
            acc[0][0] = MFMA32(a0, b0, acc[0][0]);
            acc[0][1] = MFMA32(a0, b1, acc[0][1]);
            acc[1][0] = MFMA32(a1, b0, acc[1][0]);
            acc[1][1] = MFMA32(a1, b1, acc[1][1]);
        }
    }
    // epilogue: bitmask multiply, bf16 store (L3-cached for k_pv), row sum-of-squares
#pragma unroll
    for (int mi = 0; mi < 2; ++mi) {
#pragma unroll
        for (int reg = 0; reg < 16; ++reg) {
            int rl = M0 + wy * 64 + mi * 32 + ROWOFF(reg, lh);
            long rg = (long)b * NSEQ + rl;
            float v = 0.f;
#pragma unroll
            for (int ni = 0; ni < 2; ++ni) {
                int cg = N0 + wx * 64 + ni * 32 + l31;
                u32 wd = Mb[(long)rl * 64 + (cg >> 5)];
                float s = ((wd >> l31) & 1u) ? acc[mi][ni][reg] * INV_T : 0.f;
                v += s * s;
                Sbuf[rg * NSEQ + cg] = f2bf(s);
            }
            v += __shfl_xor(v, 1, 32);
            v += __shfl_xor(v, 2, 32);
            v += __shfl_xor(v, 4, 32);
            v += __shfl_xor(v, 8, 32);
            v += __shfl_xor(v, 16, 32);
            if (l31 == 0) atomicAdd(&ssbuf[rg], v);
        }
    }
}

// ------------- kernel 3: vT[e][g] = elu(W X^T + b), 128x128 BK=64 -------------
// 512 thr / 8 waves (2x4), wave tile 64x32: doubles waves/CU (8 -> 16) on this
// 2-block/CU grid to hide the staging drain.
__global__ __launch_bounds__(512, 2) void k_vgemm(
    const u16* __restrict__ Wbf, const u16* __restrict__ Kbf,
    const float* __restrict__ bias, u16* __restrict__ vT) {
    __shared__ __attribute__((aligned(16))) u16 Ab[8192], Bb[8192];
    const int tid = threadIdx.x, wave = tid >> 6, lane = tid & 63;
    const int l31 = lane & 31, lh = lane >> 5;
    const int wy = wave >> 2, wx = wave & 3;
    const int M0 = blockIdx.y * 128, N0 = blockIdx.x * 128;
    const u16* Ag = Wbf + (long)M0 * DM;
    const u16* Bg = Kbf + (long)N0 * DM;

    f32x16 acc[2];
#pragma unroll
    for (int i = 0; i < 2; ++i)
#pragma unroll
        for (int e = 0; e < 16; ++e) acc[i][e] = 0.f;

    for (int kt = 0; kt < 8; ++kt) {
        const int k0 = kt * 64;
        __syncthreads();
        STAGE64W8(Ag, DM, Bg, DM, k0);
        __syncthreads();
#pragma unroll
        for (int ks = 0; ks < 4; ++ks) {
            const int kc = ks * 2 + lh;
            bf16x8 a0 = fragld64(Ab, wy * 64 + l31, kc);
            bf16x8 a1 = fragld64(Ab, wy * 64 + 32 + l31, kc);
            bf16x8 b0 = fragld64(Bb, wx * 32 + l31, kc);
            acc[0] = MFMA32(a0, b0, acc[0]);
            acc[1] = MFMA32(a1, b0, acc[1]);
        }
    }
#pragma unroll
    for (int mi = 0; mi < 2; ++mi) {
#pragma unroll
        for (int reg = 0; reg < 16; ++reg) {
            int e = M0 + wy * 64 + mi * 32 + ROWOFF(reg, lh);
            float bv = bias[e];
            int g = N0 + wx * 32 + l31;
            float x = acc[mi][reg] + bv;
            float v = x > 0.f ? x : (__expf(x) - 1.f);
            vT[(long)e * GTOT + g] = f2bf(v);
        }
    }
}

// -------- kernel 4: O = diag(1/max(||S_row||,eps)) * (S V), 128x128 BK=64 ------
// 512 thr / 8 waves (2x4), wave tile 64x32. 1-D grid, b = bid&7 -> XCD affinity.
__global__ __launch_bounds__(512, 2) void k_pv(
    const u16* __restrict__ Sbuf, const u16* __restrict__ vT,
    const float* __restrict__ ssbuf, float* __restrict__ Out) {
    __shared__ __attribute__((aligned(16))) u16 Ab[8192], Bb[8192];
    __shared__ float sc[128];
    const int tid = threadIdx.x, wave = tid >> 6, lane = tid & 63;
    const int l31 = lane & 31, lh = lane >> 5;
    const int wy = wave >> 2, wx = wave & 3;
    const int bid = blockIdx.x;
    const int b = bid & 7;                       // batch -> XCD
    const int r = bid >> 3;
    const int tx = r & 3, ty = r >> 2;
    const int M0 = ty * 128, N0 = tx * 128;
    const u16* Ag = Sbuf + (long)(b * NSEQ + M0) * NSEQ;
    const u16* Bg = vT + (long)N0 * GTOT + b * NSEQ;

    if (tid < 128) {
        float v = ssbuf[b * NSEQ + M0 + tid];
        sc[tid] = 1.f / fmaxf(sqrtf(v), EPSN);
    }

    f32x16 acc[2];
#pragma unroll
    for (int i = 0; i < 2; ++i)
#pragma unroll
        for (int e = 0; e < 16; ++e) acc[i][e] = 0.f;

    for (int kt = 0; kt < 32; ++kt) {
        const int k0 = kt * 64;
        __syncthreads();
        STAGE64W8(Ag, NSEQ, Bg, GTOT, k0);
        __syncthreads();
#pragma unroll
        for (int ks = 0; ks < 4; ++ks) {
            const int kc = ks * 2 + lh;
            bf16x8 a0 = fragld64(Ab, wy * 64 + l31, kc);
            bf16x8 a1 = fragld64(Ab, wy * 64 + 32 + l31, kc);
            bf16x8 b0 = fragld64(Bb, wx * 32 + l31, kc);
            acc[0] = MFMA32(a0, b0, acc[0]);
            acc[1] = MFMA32(a1, b0, acc[1]);
        }
    }
#pragma unroll
    for (int mi = 0; mi < 2; ++mi) {
#pragma unroll
        for (int reg = 0; reg < 16; ++reg) {
            int rl = wy * 64 + mi * 32 + ROWOFF(reg, lh);
            float s = sc[rl];
            int d = N0 + wx * 32 + l31;
            Out[((long)b * NSEQ + M0 + rl) * DM + d] = acc[mi][reg] * s;
        }
    }
}

extern "C" void kernel_launch(void* const* d_in, const int* in_sizes, int n_in,
                              void* d_out, int out_size, void* d_ws, size_t ws_size,
                              hipStream_t stream) {
    const float* X = (const float*)d_in[0];
    const float* mask = (const float*)d_in[1];
    const float* W = (const float*)d_in[2];
    const float* bias = (const float*)d_in[3];
    float* out = (float*)d_out;

    char* ws = (char*)d_ws;
    u16* Kbf = (u16*)ws;                           // 16 MiB
    u16* Wbf = (u16*)(ws + 16777216);              // 512 KiB
    u16* vT = (u16*)(ws + 17301504);               // 16 MiB
    u16* Sbuf = (u16*)(ws + 34078720);             // 64 MiB
    float* ssbuf = (float*)(ws + 101187584);       // 64 KiB
    u64* Mbits = (u64*)(ws + 101253120);           // 4 MiB (packed mask)

    k_convert<<<41232, 256, 0, stream>>>(X, W, mask, Kbf, Wbf, Mbits, ssbuf);
    k_vgemm<<<dim3(128, 4), 512, 0, stream>>>(Wbf, Kbf, bias, vT);
    k_sgemm<<<2048, 256, 0, stream>>>(Kbf, (const u32*)Mbits, Sbuf, ssbuf);
    k_pv<<<512, 512, 0, stream>>>(Sbuf, vT, ssbuf, out);
}

// Round 6
// 336.729 us; speedup vs baseline: 1.0895x; 1.0412x over previous
//
#include <hip/hip_runtime.h>
#include <hip/hip_bf16.h>

#define NSEQ 2048
#define DM 512
#define BATCH 8
#define GTOT (BATCH * NSEQ)          // 16384
#define INV_T 0.044194173824159216f  // 1/sqrt(512)
#define EPSN 1e-5f

typedef __bf16 bf16_t;
typedef bf16_t bf16x8 __attribute__((ext_vector_type(8)));
typedef float f32x16 __attribute__((ext_vector_type(16)));
typedef unsigned short u16;
typedef unsigned int u32;
typedef unsigned long long u64;

__device__ __forceinline__ u16 f2bf(float f) {
    u32 u = __builtin_bit_cast(u32, f);
    u32 r = (u + 0x7FFFu + ((u >> 16) & 1u)) >> 16;
    return (u16)r;
}

// async global->LDS DMA, 16 B per lane. LDS dest = wave-uniform base + lane*16 B.
__device__ __forceinline__ void async16(const u16* g, u16* l) {
    __builtin_amdgcn_global_load_lds(
        (const __attribute__((address_space(1))) u32*)g,
        (__attribute__((address_space(3))) u32*)l, 16, 0, 0);
}

// BK=64 LDS tile: rows x 64 k-elems (128 B rows), 8 16-B chunks XOR-swizzled by ((row>>1)&7).
__device__ __forceinline__ bf16x8 fragld64(const u16* t, int row, int kc) {
    return *(const bf16x8*)(t + row * 64 + ((kc ^ ((row >> 1) & 7)) << 3));
}

#define MFMA32(a, b, c) __builtin_amdgcn_mfma_f32_32x32x16_bf16(a, b, c, 0, 0, 0)
#define ROWOFF(reg, lh) (((reg) & 3) + 8 * ((reg) >> 2) + 4 * (lh))

// BK=64 staging: 8 issues/thread (4 A + 4 B). Issue u = wave*4+j covers LDS rows
// u*8..u*8+7; lane supplies row u*8+(lane>>3), chunk (lane&7), fetching the
// global chunk that fragld64's XOR expects at that slot.
#define STAGE64(Ag, ldA, Bg, ldB, k0)                                            \
    do {                                                                         \
        _Pragma("unroll") for (int j = 0; j < 4; ++j) {                          \
            const int cg = (lane & 7) ^ ((j * 4 + (lane >> 4)) & 7);             \
            const int dst = (wave * 4 + j) * 512 + lane * 8;                     \
            async16((Ag) + (long)(rS + j * 8) * (ldA) + (k0) + cg * 8, Ab + dst);\
            async16((Bg) + (long)(rS + j * 8) * (ldB) + (k0) + cg * 8, Bb + dst);\
        }                                                                        \
    } while (0)

// --- kernel 1: mask -> bits (float4 + 4 ballots), f32 -> bf16 of X/W, zero ssbuf ---
// Mask bit layout (producer-defined, consumer matches):
//   word = row*32 + (col>>8)*4 + (col&3);  bit = (col>>2) & 63.
// Wave handles a 256-col group: lane i loads float4 cols [4i..4i+3]; ballot on
// component q gives word q of the group directly.
__global__ __launch_bounds__(256) void k_convert(
    const float* __restrict__ X, const float* __restrict__ W,
    const float* __restrict__ mask, u16* __restrict__ Kbf, u16* __restrict__ Wbf,
    u64* __restrict__ Mbits, float* __restrict__ ssbuf) {
    const int bid = blockIdx.x;
    if (bid < 32768) {
        const int w = threadIdx.x >> 6, lane = threadIdx.x & 63;
        float4 f = ((const float4*)mask)[(long)bid * 256 + threadIdx.x];
        u64 b0 = __ballot(f.x != 0.f);
        u64 b1 = __ballot(f.y != 0.f);
        u64 b2 = __ballot(f.z != 0.f);
        u64 b3 = __ballot(f.w != 0.f);
        if (lane == 0) {
            u64* p = Mbits + ((long)bid * 4 + w) * 4;
            ((ulonglong2*)p)[0] = (ulonglong2){b0, b1};
            ((ulonglong2*)p)[1] = (ulonglong2){b2, b3};
        }
        return;
    }
    const long NK = (long)GTOT * DM / 4;  // 2097152
    const long NW = (long)DM * DM / 4;    // 65536
    const long NS = GTOT / 4;             // 4096
    long i = (long)(bid - 32768) * 256 + threadIdx.x;
    if (i < NK) {
        float4 f = ((const float4*)X)[i];
        ushort4 o;
        o.x = f2bf(f.x); o.y = f2bf(f.y); o.z = f2bf(f.z); o.w = f2bf(f.w);
        ((ushort4*)Kbf)[i] = o;
    } else if (i < NK + NW) {
        long j = i - NK;
        float4 f = ((const float4*)W)[j];
        ushort4 o;
        o.x = f2bf(f.x); o.y = f2bf(f.y); o.z = f2bf(f.z); o.w = f2bf(f.w);
        ((ushort4*)Wbf)[j] = o;
    } else if (i < NK + NW + NS) {
        ((float4*)ssbuf)[i - NK - NW] = (float4){0.f, 0.f, 0.f, 0.f};
    }
}

// --- kernel 2: S = bitmask .* (X X^T) * INV_T (bf16) + row sum-of-squares ---
// 128x128 tile, BK=64, 256 thr, 4 waves (2x2), wave tile 64x64 (proven optimal).
// 1-D grid, b = bid&7 -> XCD affinity (FETCH 18.6 MB measured, fully L2-resident).
__global__ __launch_bounds__(256, 4) void k_sgemm(
    const u16* __restrict__ Kbf, const u64* __restrict__ Mbits,
    u16* __restrict__ Sbuf, float* __restrict__ ssbuf) {
    __shared__ __attribute__((aligned(16))) u16 Ab[8192], Bb[8192];
    const int tid = threadIdx.x, wave = tid >> 6, lane = tid & 63;
    const int l31 = lane & 31, lh = lane >> 5;
    const int wy = wave >> 1, wx = wave & 1;
    const int bid = blockIdx.x;
    const int b = bid & 7;                       // batch -> XCD
    const int ty = (bid >> 3) & 15, tx = bid >> 7;
    const int M0 = ty * 128, N0 = tx * 128;
    const u16* Ag = Kbf + (long)(b * NSEQ + M0) * DM;
    const u16* Bg = Kbf + (long)(b * NSEQ + N0) * DM;

    const int rS = wave * 32 + (lane >> 3);

    f32x16 acc[2][2];
#pragma unroll
    for (int i = 0; i < 2; ++i)
#pragma unroll
        for (int j = 0; j < 2; ++j)
#pragma unroll
            for (int e = 0; e < 16; ++e) acc[i][j][e] = 0.f;

    for (int kt = 0; kt < 8; ++kt) {
        const int k0 = kt * 64;
        __syncthreads();
        STAGE64(Ag, DM, Bg, DM, k0);
        __syncthreads();
#pragma unroll
        for (int ks = 0; ks < 4; ++ks) {
            const int kc = ks * 2 + lh;
            bf16x8 a0 = fragld64(Ab, wy * 64 + l31, kc);
            bf16x8 a1 = fragld64(Ab, wy * 64 + 32 + l31, kc);
            bf16x8 b0 = fragld64(Bb, wx * 64 + l31, kc);
            bf16x8 b1 = fragld64(Bb, wx * 64 + 32 + l31, kc);
            acc[0][0] = MFMA32(a0, b0, acc[0][0]);
            acc[0][1] = MFMA32(a0, b1, acc[0][1]);
            acc[1][0] = MFMA32(a1, b0, acc[1][0]);
            acc[1][1] = MFMA32(a1, b1, acc[1][1]);
        }
    }
    // epilogue: bitmask multiply, bf16 store (L3-cached for k_pv), row sum-of-squares
#pragma unroll
    for (int mi = 0; mi < 2; ++mi) {
#pragma unroll
        for (int reg = 0; reg < 16; ++reg) {
            int rl = M0 + wy * 64 + mi * 32 + ROWOFF(reg, lh);
            long rg = (long)b * NSEQ + rl;
            const u64* Mr = Mbits + rg * 32;
            float v = 0.f;
#pragma unroll
            for (int ni = 0; ni < 2; ++ni) {
                int cg = N0 + wx * 64 + ni * 32 + l31;
                u64 wd = Mr[((cg >> 8) << 2) + (l31 & 3)];
                float s = ((wd >> ((cg >> 2) & 63)) & 1ull)
                              ? acc[mi][ni][reg] * INV_T : 0.f;
                v += s * s;
                Sbuf[rg * NSEQ + cg] = f2bf(s);
            }
            v += __shfl_xor(v, 1, 32);
            v += __shfl_xor(v, 2, 32);
            v += __shfl_xor(v, 4, 32);
            v += __shfl_xor(v, 8, 32);
            v += __shfl_xor(v, 16, 32);
            if (l31 == 0) atomicAdd(&ssbuf[rg], v);
        }
    }
}

// ------------- kernel 3: vT[e][g] = elu(W X^T + b), 128x128 BK=64 -------------
// Round-0 proven structure: 256 thr, 4 waves (2x2), wave tile 64x64.
__global__ __launch_bounds__(256, 4) void k_vgemm(
    const u16* __restrict__ Wbf, const u16* __restrict__ Kbf,
    const float* __restrict__ bias, u16* __restrict__ vT) {
    __shared__ __attribute__((aligned(16))) u16 Ab[8192], Bb[8192];
    const int tid = threadIdx.x, wave = tid >> 6, lane = tid & 63;
    const int l31 = lane & 31, lh = lane >> 5;
    const int wy = wave >> 1, wx = wave & 1;
    const int M0 = blockIdx.y * 128, N0 = blockIdx.x * 128;
    const u16* Ag = Wbf + (long)M0 * DM;
    const u16* Bg = Kbf + (long)N0 * DM;

    const int rS = wave * 32 + (lane >> 3);

    f32x16 acc[2][2];
#pragma unroll
    for (int i = 0; i < 2; ++i)
#pragma unroll
        for (int j = 0; j < 2; ++j)
#pragma unroll
            for (int e = 0; e < 16; ++e) acc[i][j][e] = 0.f;

    for (int kt = 0; kt < 8; ++kt) {
        const int k0 = kt * 64;
        __syncthreads();
        STAGE64(Ag, DM, Bg, DM, k0);
        __syncthreads();
#pragma unroll
        for (int ks = 0; ks < 4; ++ks) {
            const int kc = ks * 2 + lh;
            bf16x8 a0 = fragld64(Ab, wy * 64 + l31, kc);
            bf16x8 a1 = fragld64(Ab, wy * 64 + 32 + l31, kc);
            bf16x8 b0 = fragld64(Bb, wx * 64 + l31, kc);
            bf16x8 b1 = fragld64(Bb, wx * 64 + 32 + l31, kc);
            acc[0][0] = MFMA32(a0, b0, acc[0][0]);
            acc[0][1] = MFMA32(a0, b1, acc[0][1]);
            acc[1][0] = MFMA32(a1, b0, acc[1][0]);
            acc[1][1] = MFMA32(a1, b1, acc[1][1]);
        }
    }
#pragma unroll
    for (int mi = 0; mi < 2; ++mi) {
#pragma unroll
        for (int reg = 0; reg < 16; ++reg) {
            int e = M0 + wy * 64 + mi * 32 + ROWOFF(reg, lh);
            float bv = bias[e];
#pragma unroll
            for (int ni = 0; ni < 2; ++ni) {
                int g = N0 + wx * 64 + ni * 32 + l31;
                float x = acc[mi][ni][reg] + bv;
                float v = x > 0.f ? x : (__expf(x) - 1.f);
                vT[(long)e * GTOT + g] = f2bf(v);
            }
        }
    }
}

// -------- kernel 4: O = diag(1/max(||S_row||,eps)) * (S V), 128x128 BK=64 ------
// Round-3 proven structure: 256 thr, 4 waves, 1-D grid, b = bid&7 -> XCD affinity.
__global__ __launch_bounds__(256, 4) void k_pv(
    const u16* __restrict__ Sbuf, const u16* __restrict__ vT,
    const float* __restrict__ ssbuf, float* __restrict__ Out) {
    __shared__ __attribute__((aligned(16))) u16 Ab[8192], Bb[8192];
    __shared__ float sc[128];
    const int tid = threadIdx.x, wave = tid >> 6, lane = tid & 63;
    const int l31 = lane & 31, lh = lane >> 5;
    const int wy = wave >> 1, wx = wave & 1;
    const int bid = blockIdx.x;
    const int b = bid & 7;                       // batch -> XCD
    const int r = bid >> 3;
    const int tx = r & 3, ty = r >> 2;
    const int M0 = ty * 128, N0 = tx * 128;
    const u16* Ag = Sbuf + (long)(b * NSEQ + M0) * NSEQ;
    const u16* Bg = vT + (long)N0 * GTOT + b * NSEQ;

    if (tid < 128) {
        float v = ssbuf[b * NSEQ + M0 + tid];
        sc[tid] = 1.f / fmaxf(sqrtf(v), EPSN);
    }

    const int rS = wave * 32 + (lane >> 3);

    f32x16 acc[2][2];
#pragma unroll
    for (int i = 0; i < 2; ++i)
#pragma unroll
        for (int j = 0; j < 2; ++j)
#pragma unroll
            for (int e = 0; e < 16; ++e) acc[i][j][e] = 0.f;

    for (int kt = 0; kt < 32; ++kt) {
        const int k0 = kt * 64;
        __syncthreads();
        STAGE64(Ag, NSEQ, Bg, GTOT, k0);
        __syncthreads();
#pragma unroll
        for (int ks = 0; ks < 4; ++ks) {
            const int kc = ks * 2 + lh;
            bf16x8 a0 = fragld64(Ab, wy * 64 + l31, kc);
            bf16x8 a1 = fragld64(Ab, wy * 64 + 32 + l31, kc);
            bf16x8 b0 = fragld64(Bb, wx * 64 + l31, kc);
            bf16x8 b1 = fragld64(Bb, wx * 64 + 32 + l31, kc);
            acc[0][0] = MFMA32(a0, b0, acc[0][0]);
            acc[0][1] = MFMA32(a0, b1, acc[0][1]);
            acc[1][0] = MFMA32(a1, b0, acc[1][0]);
            acc[1][1] = MFMA32(a1, b1, acc[1][1]);
        }
    }
#pragma unroll
    for (int mi = 0; mi < 2; ++mi) {
#pragma unroll
        for (int reg = 0; reg < 16; ++reg) {
            int rl = wy * 64 + mi * 32 + ROWOFF(reg, lh);
            float s = sc[rl];
            float* op = Out + ((long)b * NSEQ + M0 + rl) * DM;
#pragma unroll
            for (int ni = 0; ni < 2; ++ni) {
                int d = N0 + wx * 64 + ni * 32 + l31;
                op[d] = acc[mi][ni][reg] * s;
            }
        }
    }
}

extern "C" void kernel_launch(void* const* d_in, const int* in_sizes, int n_in,
                              void* d_out, int out_size, void* d_ws, size_t ws_size,
                              hipStream_t stream) {
    const float* X = (const float*)d_in[0];
    const float* mask = (const float*)d_in[1];
    const float* W = (const float*)d_in[2];
    const float* bias = (const float*)d_in[3];
    float* out = (float*)d_out;

    char* ws = (char*)d_ws;
    u16* Kbf = (u16*)ws;                           // 16 MiB
    u16* Wbf = (u16*)(ws + 16777216);              // 512 KiB
    u16* vT = (u16*)(ws + 17301504);               // 16 MiB
    u16* Sbuf = (u16*)(ws + 34078720);             // 64 MiB
    float* ssbuf = (float*)(ws + 101187584);       // 64 KiB
    u64* Mbits = (u64*)(ws + 101253120);           // 4 MiB (packed mask)

    k_convert<<<41232, 256, 0, stream>>>(X, W, mask, Kbf, Wbf, Mbits, ssbuf);
    k_vgemm<<<dim3(128, 4), 256, 0, stream>>>(Wbf, Kbf, bias, vT);
    k_sgemm<<<2048, 256, 0, stream>>>(Kbf, Mbits, Sbuf, ssbuf);
    k_pv<<<512, 256, 0, stream>>>(Sbuf, vT, ssbuf, out);
}